// Round 1
// baseline (2225.301 us; speedup 1.0000x reference)
//
#include <hip/hip_runtime.h>

// Problem constants
#define N_   64
#define CIN  64
#define COUT 128
#define T_   300
#define V_   25
#define S_   3
#define NT   (N_ * T_)            // 19200 tiles
#define NTV  (N_ * T_ * V_)       // 480000 reduction count per channel

#define TPB_K1     4              // tiles per block in stats kernel
#define K1_BLOCKS  (NT / TPB_K1)  // 4800
#define RED_ROWS   64
#define RED_BLOCKS (K1_BLOCKS / RED_ROWS) // 75

// ws layout (in floats)
#define WS_P    0
#define WS_P2   (WS_P + K1_BLOCKS * 512)        // 4800*512
#define WS_COEF (WS_P2 + RED_BLOCKS * 512)      // 75*512
#define WS_WT   (WS_COEF + 3 * COUT)
#define WS_DWT  (WS_WT + S_ * CIN * COUT)

// ---------------------------------------------------------------------------
// K0: transpose weights for coalesced per-o access.
// WT[s][c][o] = W[s][o][c];  dWT[c][o] = down_W[o][c]
__global__ __launch_bounds__(256) void k_prep(const float* __restrict__ W,
                                              const float* __restrict__ dW,
                                              float* __restrict__ WT,
                                              float* __restrict__ dWT) {
    int i = blockIdx.x * 256 + threadIdx.x;
    if (i < S_ * CIN * COUT) {
        int s = i / (CIN * COUT);
        int r = i % (CIN * COUT);
        int c = r / COUT;
        int o = r % COUT;
        WT[i] = W[(s * COUT + o) * CIN + c];
    }
    if (i < CIN * COUT) {
        int c = i / COUT, o = i % COUT;
        dWT[i] = dW[o * CIN + c];
    }
}

// ---------------------------------------------------------------------------
// Per-(n,t) tile compute: fills acc_y[25] (pre-bias y) and acc_r[25] (pre-bias res)
// for channel o = threadIdx.x. Block = 128 threads.
__device__ __forceinline__ void tile_compute(
    const float* __restrict__ x, const float* __restrict__ WT,
    const float* __restrict__ dWT, const float* __restrict__ A_lds,
    float* __restrict__ x_lds, float* __restrict__ xa_lds,
    int n, int t, float* acc_y, float* acc_r)
{
    const int tid = threadIdx.x;
    __syncthreads();  // protect LDS reuse from previous tile / A_lds load

    // Stage x[n, :, t, :]  (CIN x V = 1600 floats)
    const float* xbase = x + (size_t)n * CIN * T_ * V_ + (size_t)t * V_;
    for (int i = tid; i < CIN * V_; i += 128) {
        int c = i / V_, v = i % V_;
        x_lds[i] = xbase[(size_t)c * (T_ * V_) + v];
    }
    __syncthreads();

    // xa[s][c][w] = sum_v x[c][v] * A_adj[s][v][w]
    for (int i = tid; i < S_ * CIN * V_; i += 128) {
        int s = i / (CIN * V_);
        int r = i % (CIN * V_);
        int c = r / V_;
        int w = r % V_;
        const float* xr = &x_lds[c * V_];
        const float* ar = &A_lds[s * V_ * V_ + w];
        float acc = 0.f;
#pragma unroll
        for (int v = 0; v < V_; ++v) acc = fmaf(xr[v], ar[v * V_], acc);
        xa_lds[i] = acc;
    }
    __syncthreads();

    const int o = tid;  // 0..127
#pragma unroll
    for (int w = 0; w < V_; ++w) { acc_y[w] = 0.f; acc_r[w] = 0.f; }

    // y[o][w] = sum_{s,c} W[s][o][c] * xa[s][c][w]
#pragma unroll 4
    for (int sc = 0; sc < S_ * CIN; ++sc) {
        float wv = WT[sc * COUT + o];          // coalesced across lanes
        const float* xr = &xa_lds[sc * V_];    // broadcast across lanes
#pragma unroll
        for (int w = 0; w < V_; ++w) acc_y[w] = fmaf(wv, xr[w], acc_y[w]);
    }
    // res[o][v] = sum_c down_W[o][c] * x[c][v]
#pragma unroll 4
    for (int c = 0; c < CIN; ++c) {
        float wv = dWT[c * COUT + o];
        const float* xr = &x_lds[c * V_];
#pragma unroll
        for (int w = 0; w < V_; ++w) acc_r[w] = fmaf(wv, xr[w], acc_r[w]);
    }
}

// ---------------------------------------------------------------------------
// K1: per-channel partial sums (Σy, Σy², Σres, Σres²) over TPB_K1 tiles/block.
__global__ __launch_bounds__(128) void k_stats(
    const float* __restrict__ x, const float* __restrict__ A,
    const float* __restrict__ alpha, const float* __restrict__ b,
    const float* __restrict__ db, const float* __restrict__ WT,
    const float* __restrict__ dWT, float* __restrict__ P)
{
    __shared__ float A_lds[S_ * V_ * V_];
    __shared__ float x_lds[CIN * V_];
    __shared__ float xa_lds[S_ * CIN * V_];
    const int tid = threadIdx.x;

    const float a0 = alpha[0];
    for (int i = tid; i < S_ * V_ * V_; i += 128) {
        int vv = i % (V_ * V_);
        int v = vv / V_, w = vv % V_;
        A_lds[i] = A[i] + (v == w ? a0 : 0.f);
    }

    const int o = tid;
    const float bsum = b[o] + b[COUT + o] + b[2 * COUT + o];
    const float dbo = db[o];

    float sy = 0.f, sy2 = 0.f, sr = 0.f, sr2 = 0.f;
    for (int it = 0; it < TPB_K1; ++it) {
        int tile = blockIdx.x * TPB_K1 + it;
        int n = tile / T_, t = tile % T_;
        float acc_y[V_], acc_r[V_];
        tile_compute(x, WT, dWT, A_lds, x_lds, xa_lds, n, t, acc_y, acc_r);
#pragma unroll
        for (int w = 0; w < V_; ++w) {
            float yv = acc_y[w] + bsum;
            float rv = acc_r[w] + dbo;
            sy += yv;  sy2 = fmaf(yv, yv, sy2);
            sr += rv;  sr2 = fmaf(rv, rv, sr2);
        }
    }
    float* p = P + (size_t)blockIdx.x * 512;
    p[o] = sy; p[128 + o] = sy2; p[256 + o] = sr; p[384 + o] = sr2;
}

// ---------------------------------------------------------------------------
// K2a: reduce 4800 partial rows -> 75 rows (deterministic).
__global__ __launch_bounds__(256) void k_red(const float* __restrict__ P,
                                             float* __restrict__ P2) {
    const int tid = threadIdx.x;
    float a0 = 0.f, a1 = 0.f;
    const int row0 = blockIdx.x * RED_ROWS;
    for (int r = 0; r < RED_ROWS; ++r) {
        const float* p = P + (size_t)(row0 + r) * 512;
        a0 += p[tid];
        a1 += p[256 + tid];
    }
    P2[blockIdx.x * 512 + tid] = a0;
    P2[blockIdx.x * 512 + 256 + tid] = a1;
}

// K2b: final reduce + BN coefficient computation.
// out = relu(ay*yv + ar*rv + c0), yv/rv include their biases.
__global__ __launch_bounds__(128) void k_coef(
    const float* __restrict__ P2, const float* __restrict__ gamma,
    const float* __restrict__ beta, const float* __restrict__ dgamma,
    const float* __restrict__ dbeta, float* __restrict__ coef) {
    const int o = threadIdx.x;
    float sy = 0.f, sy2 = 0.f, sr = 0.f, sr2 = 0.f;
    for (int r = 0; r < RED_BLOCKS; ++r) {
        const float* p = P2 + r * 512;
        sy += p[o]; sy2 += p[128 + o]; sr += p[256 + o]; sr2 += p[384 + o];
    }
    const float invn = 1.f / (float)NTV;
    float my = sy * invn, mr = sr * invn;
    float vy = fmaf(-my, my, sy2 * invn);
    float vr = fmaf(-mr, mr, sr2 * invn);
    float iy = rsqrtf(vy + 1e-5f);
    float ir = rsqrtf(vr + 1e-5f);
    float ay = iy * gamma[o];
    float ar = ir * dgamma[o];
    float c0 = beta[o] - my * ay + dbeta[o] - mr * ar;
    coef[o] = ay; coef[128 + o] = ar; coef[256 + o] = c0;
}

// ---------------------------------------------------------------------------
// K3: recompute tiles, apply fused BN+BN+ReLU epilogue, write output.
__global__ __launch_bounds__(128) void k_final(
    const float* __restrict__ x, const float* __restrict__ A,
    const float* __restrict__ alpha, const float* __restrict__ b,
    const float* __restrict__ db, const float* __restrict__ WT,
    const float* __restrict__ dWT, const float* __restrict__ coef,
    float* __restrict__ out)
{
    __shared__ float A_lds[S_ * V_ * V_];
    __shared__ float x_lds[CIN * V_];
    __shared__ float xa_lds[S_ * CIN * V_];
    const int tid = threadIdx.x;

    const float a0 = alpha[0];
    for (int i = tid; i < S_ * V_ * V_; i += 128) {
        int vv = i % (V_ * V_);
        int v = vv / V_, w = vv % V_;
        A_lds[i] = A[i] + (v == w ? a0 : 0.f);
    }

    const int tile = blockIdx.x;
    const int n = tile / T_, t = tile % T_;
    const int o = tid;

    float acc_y[V_], acc_r[V_];
    tile_compute(x, WT, dWT, A_lds, x_lds, xa_lds, n, t, acc_y, acc_r);

    const float bsum = b[o] + b[COUT + o] + b[2 * COUT + o];
    const float dbo = db[o];
    const float ay = coef[o], ar = coef[128 + o], c0 = coef[256 + o];

    float* op = out + ((size_t)(n * COUT + o) * T_ + t) * V_;
#pragma unroll
    for (int w = 0; w < V_; ++w) {
        float v = fmaf(ay, acc_y[w] + bsum, fmaf(ar, acc_r[w] + dbo, c0));
        op[w] = fmaxf(v, 0.f);
    }
}

// ---------------------------------------------------------------------------
extern "C" void kernel_launch(void* const* d_in, const int* in_sizes, int n_in,
                              void* d_out, int out_size, void* d_ws, size_t ws_size,
                              hipStream_t stream) {
    const float* x      = (const float*)d_in[0];
    const float* A      = (const float*)d_in[1];
    const float* W      = (const float*)d_in[2];
    const float* b      = (const float*)d_in[3];
    const float* alpha  = (const float*)d_in[4];
    const float* gamma  = (const float*)d_in[5];
    const float* beta   = (const float*)d_in[6];
    const float* dW     = (const float*)d_in[7];
    const float* db     = (const float*)d_in[8];
    const float* dgamma = (const float*)d_in[9];
    const float* dbeta  = (const float*)d_in[10];

    float* ws   = (float*)d_ws;
    float* P    = ws + WS_P;
    float* P2   = ws + WS_P2;
    float* coef = ws + WS_COEF;
    float* WT   = ws + WS_WT;
    float* dWT  = ws + WS_DWT;
    float* out  = (float*)d_out;

    k_prep<<<(S_ * CIN * COUT + 255) / 256, 256, 0, stream>>>(W, dW, WT, dWT);
    k_stats<<<K1_BLOCKS, 128, 0, stream>>>(x, A, alpha, b, db, WT, dWT, P);
    k_red<<<RED_BLOCKS, 256, 0, stream>>>(P, P2);
    k_coef<<<1, 128, 0, stream>>>(P2, gamma, beta, dgamma, dbeta, coef);
    k_final<<<NT, 128, 0, stream>>>(x, A, alpha, b, db, WT, dWT, coef, out);
}

// Round 2
// 644.847 us; speedup vs baseline: 3.4509x; 3.4509x over previous
//
#include <hip/hip_runtime.h>

#define N_   64
#define CIN  64
#define COUT 128
#define T_   300
#define V_   25
#define S_   3
#define NTV  (N_ * T_ * V_)       // 480000

// stats pass: TS=4, 512-thread blocks
#define NTB1   (T_ / 4)           // 75
#define NBLK1  (N_ * NTB1)        // 4800
// final pass: TS=2, 256-thread blocks
#define NTB2   (T_ / 2)           // 150
#define NBLK2  (N_ * NTB2)        // 9600

#define RED_ROWS   64
#define RED_BLOCKS (NBLK1 / RED_ROWS)   // 75

// ws layout (float offsets) — stays within the ~10.1 MB proven in round 1
#define WS_P    0
#define WS_P2   (WS_P + NBLK1 * 512)          // 2,457,600
#define WS_COEF (WS_P2 + RED_BLOCKS * 512)    // 2,496,000
#define WS_WB   (WS_COEF + 512)               // 2,496,512 (16B-aligned)
#define WS_WSB  (WS_WB + (COUT * 256) / 2)    // 2,512,896

typedef __attribute__((ext_vector_type(8))) short short8;
typedef __attribute__((ext_vector_type(4))) float f32x4;

__device__ __forceinline__ unsigned short f2bf(float f) {
    union { float f; unsigned int u; } v; v.f = f;
    unsigned int r = v.u + 0x7FFFu + ((v.u >> 16) & 1u);
    return (unsigned short)(r >> 16);
}
__device__ __forceinline__ unsigned int pack2(float lo, float hi) {
    return (unsigned int)f2bf(lo) | ((unsigned int)f2bf(hi) << 16);
}
// Zt byte-offset with XOR swizzle: row stride 512B -> spread 8 rows over 8x16B slots
__device__ __forceinline__ int zswz(int nl, int kcol) {
    int b = nl * 512 + kcol * 2;
    return b ^ ((nl & 7) << 4);
}

// ---------------------------------------------------------------------------
// K0: W_all bf16 [o=128][k=256]: k<192 -> W[s=k/64][o][c=k%64]; k>=192 -> down_W[o][k-192]
__global__ __launch_bounds__(256) void k_prep(const float* __restrict__ W,
                                              const float* __restrict__ dW,
                                              unsigned short* __restrict__ Wb) {
    int i = blockIdx.x * 256 + threadIdx.x;
    if (i < COUT * 256) {
        int o = i >> 8, k = i & 255;
        float wv = (k < 192) ? W[((k >> 6) * COUT + o) * CIN + (k & 63)]
                             : dW[o * CIN + (k - 192)];
        Wb[i] = f2bf(wv);
    }
}

// K4: scaled weights for pass 2: rows k<192 scaled by ay[o], k>=192 by ar[o]
__global__ __launch_bounds__(256) void k_prep2(const float* __restrict__ W,
                                               const float* __restrict__ dW,
                                               const float* __restrict__ coef,
                                               unsigned short* __restrict__ Wsb) {
    int i = blockIdx.x * 256 + threadIdx.x;
    if (i < COUT * 256) {
        int o = i >> 8, k = i & 255;
        float wv = (k < 192) ? W[((k >> 6) * COUT + o) * CIN + (k & 63)]
                             : dW[o * CIN + (k - 192)];
        float sc = (k < 192) ? coef[o] : coef[COUT + o];
        Wsb[i] = f2bf(sc * wv);
    }
}

// ---------------------------------------------------------------------------
// Main GEMM kernel. TSP time-steps per block, 2*TSP waves (128*TSP threads).
// Wave (mh, nh): o-half mh (64 rows), time-slot nh. Per-wave tile 64x32, K=256.
template<int TSP, bool STATS>
__global__ __launch_bounds__(128 * TSP, TSP == 2 ? 3 : 2) void k_gemm(
    const float* __restrict__ x, const float* __restrict__ A,
    const float* __restrict__ alpha, const unsigned short* __restrict__ Wb,
    const float* __restrict__ coef, float* __restrict__ P,
    float* __restrict__ out)
{
    __shared__ __align__(16) unsigned short Zt[TSP * 32 * 256];  // [n_local][k] bf16, swizzled
    __shared__ float sbuf[TSP * 128 * 4];
    char* zb = (char*)Zt;

    const int tid = threadIdx.x;
    const int wid = tid >> 6, lane = tid & 63;
    const int lq = lane >> 4, lr = lane & 15;
    const int mh = wid / TSP, nh = wid % TSP;

    const int bid = blockIdx.x;
    const int n = bid / (T_ / TSP), tb = bid % (T_ / TSP);
    const int t0 = tb * TSP;
    const int t = t0 + nh;

    // ---- Phase A: build Zt ----
    // x-part: Zt[tl*32+v][192+c] = x[n][c][t0+tl][v]
    for (int i = tid; i < CIN * TSP * V_; i += 128 * TSP) {
        int c = i / (TSP * V_);
        int tv = i % (TSP * V_);
        int tl = tv / V_, v = tv % V_;
        float f = x[(((size_t)n * CIN + c) * T_ + t0 + tl) * V_ + v];
        *(unsigned short*)(zb + zswz(tl * 32 + v, 192 + c)) = f2bf(f);
    }

    // XA-part via MFMA: XA[s*64+c][tl*32+w] = sum_v x[c][t][v] * A_adj[s][v][w]
    {
        short8 xf[2];
#pragma unroll
        for (int mi = 0; mi < 2; ++mi) {
            int c = mh * 32 + mi * 16 + lr;
            const float* xr = x + (((size_t)n * CIN + c) * T_ + t) * V_;
#pragma unroll
            for (int j = 0; j < 8; ++j) {
                int v = lq * 8 + j;
                float f = (v < V_) ? xr[v] : 0.f;
                xf[mi][j] = (short)f2bf(f);
            }
        }
        const float a0 = alpha[0];
        short8 abf[S_][2];
#pragma unroll
        for (int s = 0; s < S_; ++s)
#pragma unroll
            for (int nf = 0; nf < 2; ++nf)
#pragma unroll
                for (int j = 0; j < 8; ++j) {
                    int v = lq * 8 + j, w = nf * 16 + lr;
                    float f = (v < V_ && w < V_)
                                ? A[(s * V_ + v) * V_ + w] + ((v == w) ? a0 : 0.f)
                                : 0.f;
                    abf[s][nf][j] = (short)f2bf(f);
                }
#pragma unroll
        for (int s = 0; s < S_; ++s)
#pragma unroll
            for (int mi = 0; mi < 2; ++mi)
#pragma unroll
                for (int nf = 0; nf < 2; ++nf) {
                    f32x4 d = {0.f, 0.f, 0.f, 0.f};
                    d = __builtin_amdgcn_mfma_f32_16x16x32_bf16(xf[mi], abf[s][nf], d, 0, 0, 0);
                    int nl = nh * 32 + nf * 16 + lr;
                    int kc = s * 64 + mh * 32 + mi * 16 + lq * 4;
                    unsigned long long pk = (unsigned long long)pack2(d[0], d[1])
                                          | ((unsigned long long)pack2(d[2], d[3]) << 32);
                    *(unsigned long long*)(zb + zswz(nl, kc)) = pk;
                }
    }
    __syncthreads();

    // ---- Phase B: K-loop, 8 k-steps of 32 ----
    f32x4 acc_y[4][2], acc_r[4][2];
#pragma unroll
    for (int mi = 0; mi < 4; ++mi)
#pragma unroll
        for (int nf = 0; nf < 2; ++nf) {
            acc_y[mi][nf] = (f32x4){0.f, 0.f, 0.f, 0.f};
            if (STATS) acc_r[mi][nf] = (f32x4){0.f, 0.f, 0.f, 0.f};
        }

#pragma unroll
    for (int ks = 0; ks < 8; ++ks) {
        short8 wf[4];
#pragma unroll
        for (int mi = 0; mi < 4; ++mi) {
            int o = mh * 64 + mi * 16 + lr;
            wf[mi] = *(const short8*)(Wb + (size_t)o * 256 + ks * 32 + lq * 8);
        }
        short8 bfg[2];
#pragma unroll
        for (int nf = 0; nf < 2; ++nf) {
            int nl = nh * 32 + nf * 16 + lr;
            bfg[nf] = *(const short8*)(zb + zswz(nl, ks * 32 + lq * 8));
        }
#pragma unroll
        for (int mi = 0; mi < 4; ++mi)
#pragma unroll
            for (int nf = 0; nf < 2; ++nf) {
                if (STATS && ks >= 6)
                    acc_r[mi][nf] = __builtin_amdgcn_mfma_f32_16x16x32_bf16(wf[mi], bfg[nf], acc_r[mi][nf], 0, 0, 0);
                else
                    acc_y[mi][nf] = __builtin_amdgcn_mfma_f32_16x16x32_bf16(wf[mi], bfg[nf], acc_y[mi][nf], 0, 0, 0);
            }
    }

    // ---- Epilogue ----
    if constexpr (STATS) {
        // masked per-channel partial sums (w<25): acc_y holds y_raw (k<192), acc_r res_raw
#pragma unroll
        for (int mi = 0; mi < 4; ++mi)
#pragma unroll
            for (int r = 0; r < 4; ++r) {
                float y0 = acc_y[mi][0][r], y1 = (lr < 9) ? acc_y[mi][1][r] : 0.f;
                float r0 = acc_r[mi][0][r], r1 = (lr < 9) ? acc_r[mi][1][r] : 0.f;
                float sy = y0 + y1, sy2 = y0 * y0 + y1 * y1;
                float sr = r0 + r1, sr2 = r0 * r0 + r1 * r1;
#pragma unroll
                for (int d = 1; d < 16; d <<= 1) {
                    sy  += __shfl_xor(sy, d, 64);
                    sy2 += __shfl_xor(sy2, d, 64);
                    sr  += __shfl_xor(sr, d, 64);
                    sr2 += __shfl_xor(sr2, d, 64);
                }
                if (lr == 0) {
                    int o = mh * 64 + mi * 16 + lq * 4 + r;
                    float* sb = &sbuf[(nh * 128 + o) * 4];
                    sb[0] = sy; sb[1] = sy2; sb[2] = sr; sb[3] = sr2;
                }
            }
        __syncthreads();
        for (int i = tid; i < 512; i += 128 * TSP) {
            int st = i >> 7, o = i & 127;
            float acc = 0.f;
#pragma unroll
            for (int sl = 0; sl < TSP; ++sl) acc += sbuf[(sl * 128 + o) * 4 + st];
            P[(size_t)bid * 512 + st * 128 + o] = acc;
        }
    } else {
        // out = relu(acc + c0''[o]) at [n][o][t][w], valid w<25
#pragma unroll
        for (int mi = 0; mi < 4; ++mi) {
#pragma unroll
            for (int r = 0; r < 4; ++r) {
                int o = mh * 64 + mi * 16 + lq * 4 + r;
                float c0 = coef[2 * COUT + o];
                float* op = out + (((size_t)(n * COUT + o)) * T_ + t) * V_;
                float v0 = fmaxf(acc_y[mi][0][r] + c0, 0.f);
                op[lr] = v0;
                if (lr < 9) {
                    float v1 = fmaxf(acc_y[mi][1][r] + c0, 0.f);
                    op[16 + lr] = v1;
                }
            }
        }
    }
}

// ---------------------------------------------------------------------------
__global__ __launch_bounds__(256) void k_red(const float* __restrict__ P,
                                             float* __restrict__ P2) {
    const int tid = threadIdx.x;
    float a0 = 0.f, a1 = 0.f;
    const int row0 = blockIdx.x * RED_ROWS;
    for (int r = 0; r < RED_ROWS; ++r) {
        const float* p = P + (size_t)(row0 + r) * 512;
        a0 += p[tid];
        a1 += p[256 + tid];
    }
    P2[blockIdx.x * 512 + tid] = a0;
    P2[blockIdx.x * 512 + 256 + tid] = a1;
}

__global__ __launch_bounds__(128) void k_coef(
    const float* __restrict__ P2, const float* __restrict__ gamma,
    const float* __restrict__ beta, const float* __restrict__ dgamma,
    const float* __restrict__ dbeta, const float* __restrict__ b,
    const float* __restrict__ db, float* __restrict__ coef) {
    const int o = threadIdx.x;
    float sy = 0.f, sy2 = 0.f, sr = 0.f, sr2 = 0.f;
    for (int r2 = 0; r2 < RED_BLOCKS; ++r2) {
        const float* p = P2 + r2 * 512;
        sy += p[o]; sy2 += p[128 + o]; sr += p[256 + o]; sr2 += p[384 + o];
    }
    const float bsum = b[o] + b[COUT + o] + b[2 * COUT + o];
    const float dbo = db[o];
    // stats were of raw (pre-bias) values; fold biases analytically
    float syb  = sy + (float)NTV * bsum;
    float sy2b = sy2 + 2.f * bsum * sy + (float)NTV * bsum * bsum;
    float srb  = sr + (float)NTV * dbo;
    float sr2b = sr2 + 2.f * dbo * sr + (float)NTV * dbo * dbo;
    const float invn = 1.f / (float)NTV;
    float my = syb * invn, mr = srb * invn;
    float vy = fmaf(-my, my, sy2b * invn);
    float vr = fmaf(-mr, mr, sr2b * invn);
    float ay = rsqrtf(vy + 1e-5f) * gamma[o];
    float ar = rsqrtf(vr + 1e-5f) * dgamma[o];
    float c0 = beta[o] - my * ay + dbeta[o] - mr * ar + ay * bsum + ar * dbo;
    coef[o] = ay; coef[COUT + o] = ar; coef[2 * COUT + o] = c0;
}

// ---------------------------------------------------------------------------
extern "C" void kernel_launch(void* const* d_in, const int* in_sizes, int n_in,
                              void* d_out, int out_size, void* d_ws, size_t ws_size,
                              hipStream_t stream) {
    const float* x      = (const float*)d_in[0];
    const float* A      = (const float*)d_in[1];
    const float* W      = (const float*)d_in[2];
    const float* b      = (const float*)d_in[3];
    const float* alpha  = (const float*)d_in[4];
    const float* gamma  = (const float*)d_in[5];
    const float* beta   = (const float*)d_in[6];
    const float* dW     = (const float*)d_in[7];
    const float* db     = (const float*)d_in[8];
    const float* dgamma = (const float*)d_in[9];
    const float* dbeta  = (const float*)d_in[10];

    float* ws   = (float*)d_ws;
    float* P    = ws + WS_P;
    float* P2   = ws + WS_P2;
    float* coef = ws + WS_COEF;
    unsigned short* Wb  = (unsigned short*)(ws + WS_WB);
    unsigned short* Wsb = (unsigned short*)(ws + WS_WSB);
    float* out  = (float*)d_out;

    k_prep<<<(COUT * 256 + 255) / 256, 256, 0, stream>>>(W, dW, Wb);
    k_gemm<4, true><<<NBLK1, 512, 0, stream>>>(x, A, alpha, Wb, nullptr, P, nullptr);
    k_red<<<RED_BLOCKS, 256, 0, stream>>>(P, P2);
    k_coef<<<1, 128, 0, stream>>>(P2, gamma, beta, dgamma, dbeta, b, db, coef);
    k_prep2<<<(COUT * 256 + 255) / 256, 256, 0, stream>>>(W, dW, coef, Wsb);
    k_gemm<2, false><<<NBLK2, 256, 0, stream>>>(x, A, alpha, Wsb, coef, nullptr, out);
}

// Round 3
// 249.099 us; speedup vs baseline: 8.9334x; 2.5887x over previous
//
#include <hip/hip_runtime.h>
#include <hip/hip_bf16.h>

#define N_   64
#define CIN  64
#define COUT 128
#define T_   300
#define V_   25
#define S_   3
#define NTV  (N_ * T_ * V_)       // 480000

#define TS     10
#define NTB    (T_ / TS)          // 30
#define NBLK   (N_ * NTB)         // 1920
#define RED_ROWS   64
#define RED_BLOCKS (NBLK / RED_ROWS)  // 30

// ws layout (float offsets), ~4.1 MB total
#define WS_P    0
#define WS_P2   (WS_P + NBLK * 512)          // 983040
#define WS_COEF (WS_P2 + RED_BLOCKS * 512)   // 998400
#define WS_WF   (WS_COEF + 512)              // 998912 (16B aligned)
#define WS_WSF  (WS_WF + 16384)
#define WS_AF   (WS_WSF + 16384)

typedef __attribute__((ext_vector_type(8))) short short8;
typedef __attribute__((ext_vector_type(4))) float f32x4;

__device__ __forceinline__ unsigned short bfbits(float f) {
    union { __hip_bfloat16 h; unsigned short u; } cv;
    cv.h = __float2bfloat16(f);
    return cv.u;
}

// Z tile byte offset: 32 rows x 256 bf16 cols (512 B rows), full-row XOR swizzle.
// 16B slot index ^= (row & 31): column accesses spread across all 32 slots.
__device__ __forceinline__ int zoff(int nl, int k) {
    int slot = (k >> 3) ^ (nl & 31);
    return nl * 512 + slot * 16 + (k & 7) * 2;
}

// ---------------------------------------------------------------------------
// k_prep: W fragment table (B-operand layout) + A_adj^T fragment table.
// Wf[((oh*2+of)*8+ks)*64+lane][8]: value W_all[o = oh*32+of*16+(lane&15)][k = ks*32+(lane>>4)*8+j]
//   W_all[o][k] = k<192 ? W[k/64][o][k%64] : down_W[o][k-192]
// Af[((s*2+wf)*64+lane)][8]: A_adj[v = (lane>>4)*8+j][w = wf*16+(lane&15)], zero-padded
__global__ __launch_bounds__(256) void k_prep(const float* __restrict__ W,
                                              const float* __restrict__ dW,
                                              const float* __restrict__ A,
                                              const float* __restrict__ alpha,
                                              unsigned short* __restrict__ Wf,
                                              unsigned short* __restrict__ Af) {
    int i = blockIdx.x * 256 + threadIdx.x;  // 32768
    {
        int j = i & 7, lane = (i >> 3) & 63, ks = (i >> 9) & 7;
        int of = (i >> 12) & 1, oh = i >> 13;
        int lq = lane >> 4, lr = lane & 15;
        int o = oh * 32 + of * 16 + lr;
        int k = ks * 32 + lq * 8 + j;
        float wv = (k < 192) ? W[(k >> 6) * (COUT * CIN) + o * CIN + (k & 63)]
                             : dW[o * CIN + (k - 192)];
        Wf[i] = bfbits(wv);
    }
    if (i < 3072) {
        int j = i & 7, lane = (i >> 3) & 63, wf = (i >> 9) & 1, s = i >> 10;
        int lq = lane >> 4, lr = lane & 15;
        int v = lq * 8 + j, w = wf * 16 + lr;
        float av = (v < V_ && w < V_)
                     ? A[(s * V_ + v) * V_ + w] + ((v == w) ? alpha[0] : 0.f)
                     : 0.f;
        Af[i] = bfbits(av);
    }
}

// k_prep2: same W table but rows k<192 scaled by ay[o], k>=192 by ar[o]
__global__ __launch_bounds__(256) void k_prep2(const float* __restrict__ W,
                                               const float* __restrict__ dW,
                                               const float* __restrict__ coef,
                                               unsigned short* __restrict__ Wsf) {
    int i = blockIdx.x * 256 + threadIdx.x;
    int j = i & 7, lane = (i >> 3) & 63, ks = (i >> 9) & 7;
    int of = (i >> 12) & 1, oh = i >> 13;
    int lq = lane >> 4, lr = lane & 15;
    int o = oh * 32 + of * 16 + lr;
    int k = ks * 32 + lq * 8 + j;
    float wv = (k < 192) ? W[(k >> 6) * (COUT * CIN) + o * CIN + (k & 63)]
                         : dW[o * CIN + (k - 192)];
    float sc = (k < 192) ? coef[o] : coef[COUT + o];
    Wsf[i] = bfbits(wv * sc);
    (void)j;
}

// ---------------------------------------------------------------------------
// Per-t-step staging: x-part (transposed via register layout) + XA via MFMA.
__device__ __forceinline__ void stage(char* zb, const unsigned short* Alds,
                                      f32x4 a0, f32x4 a1, float x24,
                                      int oh, int lq, int lr, int lane)
{
    const bool q3 = (lq == 3);
    float f[8];
    f[0] = q3 ? x24 : a0[0];
    f[1] = q3 ? 0.f : a0[1];
    f[2] = q3 ? 0.f : a0[2];
    f[3] = q3 ? 0.f : a0[3];
    f[4] = q3 ? 0.f : a1[0];
    f[5] = q3 ? 0.f : a1[1];
    f[6] = q3 ? 0.f : a1[2];
    f[7] = q3 ? 0.f : a1[3];

    short8 xfr;
    const int kc = 192 + oh * 16 + lr;
#pragma unroll
    for (int j = 0; j < 8; ++j) {
        unsigned short e = bfbits(f[j]);
        xfr[j] = (short)e;
        *(unsigned short*)(zb + zoff(lq * 8 + j, kc)) = e;  // rows v>=25 get zeros
    }

    const f32x4 zero = {0.f, 0.f, 0.f, 0.f};
    const int kc2 = oh * 16 + lr;
#pragma unroll
    for (int s = 0; s < S_; ++s)
#pragma unroll
        for (int wf = 0; wf < 2; ++wf) {
            short8 af = *(const short8*)(Alds + ((s * 2 + wf) * 64 + lane) * 8);
            f32x4 d = __builtin_amdgcn_mfma_f32_16x16x32_bf16(af, xfr, zero, 0, 0, 0);
#pragma unroll
            for (int r = 0; r < 4; ++r)
                *(unsigned short*)(zb + zoff(wf * 16 + lq * 4 + r, s * 64 + kc2)) = bfbits(d[r]);
        }
}

// ---------------------------------------------------------------------------
// Main kernel: 256 threads = 4 waves (wave oh owns o in [oh*32, oh*32+32)).
// Per t-step: Z = [w(32 rows) x k(256)]: k<192 = XA, k>=192 = x. One GEMM
// (A=Z rows, B=W frags in regs) produces y (ks<6) and res (ks 6,7).
template<bool STATS>
__global__ __launch_bounds__(256, 3) void k_gemm(
    const float* __restrict__ x, const unsigned short* __restrict__ Wf,
    const unsigned short* __restrict__ Af, const float* __restrict__ coef,
    float* __restrict__ P, float* __restrict__ out)
{
    __shared__ __align__(16) unsigned short Zt[2][32 * 256];   // 32 KB dbuf
    __shared__ __align__(16) unsigned short Alds[6 * 64 * 8];  // 6 KB

    const int tid = threadIdx.x;
    const int oh = tid >> 6, lane = tid & 63;
    const int lq = lane >> 4, lr = lane & 15;

    const int bid = blockIdx.x;
    const int n = bid / NTB, tb = bid % NTB;
    const int t0 = tb * TS;

    for (int i = tid; i < 384; i += 256)
        *(short8*)(Alds + i * 8) = *(const short8*)(Af + i * 8);

    short8 wfr[2][8];
#pragma unroll
    for (int of = 0; of < 2; ++of)
#pragma unroll
        for (int ks = 0; ks < 8; ++ks)
            wfr[of][ks] = *(const short8*)(Wf + (((oh * 2 + of) * 8 + ks) * 64 + lane) * 8);

    float c0v[2] = {0.f, 0.f};
    if (!STATS) {
        c0v[0] = coef[2 * COUT + oh * 32 + lr];
        c0v[1] = coef[2 * COUT + oh * 32 + 16 + lr];
    }

    float sy[2] = {0.f, 0.f}, sy2[2] = {0.f, 0.f};
    float sr[2] = {0.f, 0.f}, sr2[2] = {0.f, 0.f};

    const int c = oh * 16 + lr;
    const float* xrow = x + ((size_t)(n * CIN + c) * T_) * V_;
    const int vb = (lq < 3) ? lq * 8 : 16;

    __syncthreads();  // Alds ready

    {   // prologue: stage t0 into buf0
        const float* base = xrow + (size_t)t0 * V_;
        f32x4 a0 = *(const f32x4*)(base + vb);
        f32x4 a1 = *(const f32x4*)(base + vb + 4);
        float x24 = base[24];
        stage((char*)Zt[0], Alds, a0, a1, x24, oh, lq, lr, lane);
    }

    const f32x4 zero = {0.f, 0.f, 0.f, 0.f};

    for (int tt = 0; tt < TS; ++tt) {
        const int t = t0 + tt;
        char* zb = (char*)Zt[tt & 1];
        __syncthreads();

        // early-issue next tile's x loads (T14)
        f32x4 pa0 = zero, pa1 = zero; float px24 = 0.f;
        if (tt + 1 < TS) {
            const float* base = xrow + (size_t)(t + 1) * V_;
            pa0 = *(const f32x4*)(base + vb);
            pa1 = *(const f32x4*)(base + vb + 4);
            px24 = base[24];
        }

        // main GEMM: 16 ds_read_b128 + 32 MFMA
        f32x4 acc[2][2], accr[2][2];
#pragma unroll
        for (int ks = 0; ks < 8; ++ks) {
            short8 za[2];
            za[0] = *(const short8*)(zb + zoff(lr, ks * 32 + lq * 8));
            za[1] = *(const short8*)(zb + zoff(16 + lr, ks * 32 + lq * 8));
            if constexpr (STATS) {
                if (ks < 6) {
#pragma unroll
                    for (int mf = 0; mf < 2; ++mf)
#pragma unroll
                        for (int of = 0; of < 2; ++of)
                            acc[mf][of] = __builtin_amdgcn_mfma_f32_16x16x32_bf16(
                                za[mf], wfr[of][ks], ks == 0 ? zero : acc[mf][of], 0, 0, 0);
                } else {
#pragma unroll
                    for (int mf = 0; mf < 2; ++mf)
#pragma unroll
                        for (int of = 0; of < 2; ++of)
                            accr[mf][of] = __builtin_amdgcn_mfma_f32_16x16x32_bf16(
                                za[mf], wfr[of][ks], ks == 6 ? zero : accr[mf][of], 0, 0, 0);
                }
            } else {
#pragma unroll
                for (int mf = 0; mf < 2; ++mf)
#pragma unroll
                    for (int of = 0; of < 2; ++of)
                        acc[mf][of] = __builtin_amdgcn_mfma_f32_16x16x32_bf16(
                            za[mf], wfr[of][ks], ks == 0 ? zero : acc[mf][of], 0, 0, 0);
            }
        }

        // stage next tile into the other buffer (overlaps with epilogue VALU)
        if (tt + 1 < TS)
            stage((char*)Zt[(tt + 1) & 1], Alds, pa0, pa1, px24, oh, lq, lr, lane);

        if constexpr (STATS) {
#pragma unroll
            for (int of = 0; of < 2; ++of)
#pragma unroll
                for (int mf = 0; mf < 2; ++mf)
#pragma unroll
                    for (int r = 0; r < 4; ++r) {
                        float yv = acc[mf][of][r];
                        sy[of] += yv; sy2[of] = fmaf(yv, yv, sy2[of]);
                        float rv = accr[mf][of][r];
                        sr[of] += rv; sr2[of] = fmaf(rv, rv, sr2[of]);
                    }
        } else {
#pragma unroll
            for (int of = 0; of < 2; ++of) {
                int o = oh * 32 + of * 16 + lr;
                float* rowp = out + ((size_t)(n * COUT + o) * T_ + t) * V_;
                f32x4 v0;
#pragma unroll
                for (int r = 0; r < 4; ++r) v0[r] = fmaxf(acc[0][of][r] + c0v[of], 0.f);
                *(f32x4*)(rowp + lq * 4) = v0;           // w = lq*4..lq*4+3 (<16)
                if (lq < 2) {
                    f32x4 v1;
#pragma unroll
                    for (int r = 0; r < 4; ++r) v1[r] = fmaxf(acc[1][of][r] + c0v[of], 0.f);
                    *(f32x4*)(rowp + 16 + lq * 4) = v1;  // w = 16..23
                } else if (lq == 2) {
                    rowp[24] = fmaxf(acc[1][of][0] + c0v[of], 0.f);  // w = 24
                }
            }
        }
    }

    if constexpr (STATS) {
#pragma unroll
        for (int of = 0; of < 2; ++of) {
            sy[of]  += __shfl_xor(sy[of], 16);  sy[of]  += __shfl_xor(sy[of], 32);
            sy2[of] += __shfl_xor(sy2[of], 16); sy2[of] += __shfl_xor(sy2[of], 32);
            sr[of]  += __shfl_xor(sr[of], 16);  sr[of]  += __shfl_xor(sr[of], 32);
            sr2[of] += __shfl_xor(sr2[of], 16); sr2[of] += __shfl_xor(sr2[of], 32);
        }
        if (lq == 0) {
            float* p = P + (size_t)bid * 512;
#pragma unroll
            for (int of = 0; of < 2; ++of) {
                int o = oh * 32 + of * 16 + lr;
                p[o] = sy[of]; p[128 + o] = sy2[of];
                p[256 + o] = sr[of]; p[384 + o] = sr2[of];
            }
        }
    }
}

// ---------------------------------------------------------------------------
__global__ __launch_bounds__(256) void k_red(const float* __restrict__ P,
                                             float* __restrict__ P2) {
    const int tid = threadIdx.x;
    float a0 = 0.f, a1 = 0.f;
    const int row0 = blockIdx.x * RED_ROWS;
    for (int r = 0; r < RED_ROWS; ++r) {
        const float* p = P + (size_t)(row0 + r) * 512;
        a0 += p[tid];
        a1 += p[256 + tid];
    }
    P2[blockIdx.x * 512 + tid] = a0;
    P2[blockIdx.x * 512 + 256 + tid] = a1;
}

__global__ __launch_bounds__(128) void k_coef(
    const float* __restrict__ P2, const float* __restrict__ gamma,
    const float* __restrict__ beta, const float* __restrict__ dgamma,
    const float* __restrict__ dbeta, const float* __restrict__ b,
    const float* __restrict__ db, float* __restrict__ coef) {
    const int o = threadIdx.x;
    float sy = 0.f, sy2 = 0.f, sr = 0.f, sr2 = 0.f;
    for (int r2 = 0; r2 < RED_BLOCKS; ++r2) {
        const float* p = P2 + r2 * 512;
        sy += p[o]; sy2 += p[128 + o]; sr += p[256 + o]; sr2 += p[384 + o];
    }
    const float bsum = b[o] + b[COUT + o] + b[2 * COUT + o];
    const float dbo = db[o];
    float syb  = sy + (float)NTV * bsum;
    float sy2b = sy2 + 2.f * bsum * sy + (float)NTV * bsum * bsum;
    float srb  = sr + (float)NTV * dbo;
    float sr2b = sr2 + 2.f * dbo * sr + (float)NTV * dbo * dbo;
    const float invn = 1.f / (float)NTV;
    float my = syb * invn, mr = srb * invn;
    float vy = fmaf(-my, my, sy2b * invn);
    float vr = fmaf(-mr, mr, sr2b * invn);
    float ay = rsqrtf(vy + 1e-5f) * gamma[o];
    float ar = rsqrtf(vr + 1e-5f) * dgamma[o];
    float c0 = beta[o] - my * ay + dbeta[o] - mr * ar + ay * bsum + ar * dbo;
    coef[o] = ay; coef[COUT + o] = ar; coef[2 * COUT + o] = c0;
}

// ---------------------------------------------------------------------------
extern "C" void kernel_launch(void* const* d_in, const int* in_sizes, int n_in,
                              void* d_out, int out_size, void* d_ws, size_t ws_size,
                              hipStream_t stream) {
    const float* x      = (const float*)d_in[0];
    const float* A      = (const float*)d_in[1];
    const float* W      = (const float*)d_in[2];
    const float* b      = (const float*)d_in[3];
    const float* alpha  = (const float*)d_in[4];
    const float* gamma  = (const float*)d_in[5];
    const float* beta   = (const float*)d_in[6];
    const float* dW     = (const float*)d_in[7];
    const float* db     = (const float*)d_in[8];
    const float* dgamma = (const float*)d_in[9];
    const float* dbeta  = (const float*)d_in[10];

    float* ws   = (float*)d_ws;
    float* P    = ws + WS_P;
    float* P2   = ws + WS_P2;
    float* coef = ws + WS_COEF;
    unsigned short* Wf  = (unsigned short*)(ws + WS_WF);
    unsigned short* Wsf = (unsigned short*)(ws + WS_WSF);
    unsigned short* Af  = (unsigned short*)(ws + WS_AF);
    float* out  = (float*)d_out;

    k_prep<<<128, 256, 0, stream>>>(W, dW, A, alpha, Wf, Af);
    k_gemm<true><<<NBLK, 256, 0, stream>>>(x, Wf, Af, nullptr, P, nullptr);
    k_red<<<RED_BLOCKS, 256, 0, stream>>>(P, P2);
    k_coef<<<1, 128, 0, stream>>>(P2, gamma, beta, dgamma, dbeta, b, db, coef);
    k_prep2<<<128, 256, 0, stream>>>(W, dW, coef, Wsf);
    k_gemm<false><<<NBLK, 256, 0, stream>>>(x, Wsf, Af, coef, nullptr, out);
}